// Round 6
// baseline (106.896 us; speedup 1.0000x reference)
//
#include <hip/hip_runtime.h>
#include <hip/hip_bf16.h>
#include <math.h>

#define B_ 8
#define H_ 128
#define W_ 128
#define C_ 3
#define D_ 132
#define HW_ (H_*W_)            // 16384
#define RPB_ (HW_+1)           // 16385 rows per batch (incl. zero row)
#define NROWS_ (B_*RPB_)       // 131080
#define AROWS_ 131136          // 2049*64, slack so last tile can stage
#define FSTRIDE_ 136           // bf16 row stride for flat_ext AND z_ext (272 B)
#define MSTRIDE_ 168           // M row stride (zeros at k>=132)
#define NK_ 65536
#define NOUT_ (B_*NK_)         // 524288
#define MELEMS_ 24576          // M buffer elems (49152 B = 48 chunks of 1 KiB)

typedef __attribute__((ext_vector_type(8))) short short8v;
typedef __attribute__((ext_vector_type(8))) unsigned short ushort8v;
typedef __attribute__((ext_vector_type(4))) float f32x4;

#define GLOAD16(gp, lp) __builtin_amdgcn_global_load_lds( \
  (const __attribute__((address_space(1))) unsigned int*)(gp), \
  (__attribute__((address_space(3))) unsigned int*)(void*)(lp), 16, 0, 0)

__device__ inline float bf2f(unsigned short u) {
  return __uint_as_float(((unsigned)u) << 16);
}
__device__ inline unsigned short f2bf(float f) {
  __hip_bfloat16 hb = __float2bfloat16(f);
  return *(unsigned short*)&hb;
}

// ---------------------------------------------------------------------------
// K0: M_bf16[a][k], padded [146][168].
//   a<132:  M[a][k] = sum_o ks_w[o][a] * qs_w[o][k]
//   a==132: u[k] (z col 132 = su);  a==133: v[k] (z col 133 = sv); else 0.
//   c = ks_b . qs_b (f32).
// ---------------------------------------------------------------------------
__global__ __launch_bounds__(256) void prep_kernel(
    const float* __restrict__ ks_w, const float* __restrict__ ks_b,
    const float* __restrict__ qs_w, const float* __restrict__ qs_b,
    unsigned short* __restrict__ Mb, float* __restrict__ cc) {
  int idx = blockIdx.x * 256 + threadIdx.x;
  if (idx >= MELEMS_) return;
  int a = idx / MSTRIDE_;
  int k = idx - a * MSTRIDE_;
  float val = 0.f;
  if (k < D_) {
    if (a < D_) {
      for (int o = 0; o < D_; ++o)
        val = fmaf(ks_w[o * D_ + a], qs_w[o * D_ + k], val);
    } else if (a == 132) {
      for (int o = 0; o < D_; ++o)
        val = fmaf(qs_b[o], ks_w[o * D_ + k], val);
    } else if (a == 133) {
      for (int o = 0; o < D_; ++o)
        val = fmaf(ks_b[o], qs_w[o * D_ + k], val);
    }
  }
  Mb[idx] = f2bf(val);
  if (idx == 0) {
    float s = 0.f;
    for (int o = 0; o < D_; ++o) s = fmaf(ks_b[o], qs_b[o], s);
    cc[0] = s;
  }
}

// ---------------------------------------------------------------------------
// K1 v3: 3x3 SAME conv + bias + L2-norm over W, write bf16 flat_ext rows
// [f(132), 1.0, 0(su placeholder), 0, 0], stride 136.
// 512 threads, 1056 items of (wg 0..7 x d 0..131), item = wg*132 + d.
// Thread t does items {t, t+512, t+1024 if t<32}, 16 w-outputs each.
// __launch_bounds__(512,4) pins VGPR<=128 -> 2 blocks/CU = 16 waves/CU.
// ---------------------------------------------------------------------------
__global__ __launch_bounds__(512, 4) void conv_norm_kernel(
    const float* __restrict__ img, const float* __restrict__ cw,
    const float* __restrict__ cb, unsigned short* __restrict__ flat) {
  int bid = blockIdx.x;
  int tid = threadIdx.x;
  if (bid >= B_ * H_) {
    // zero row 16384 of every batch: [0 x132, 1.0, 0, 0, 0]
    for (int i = tid; i < B_ * FSTRIDE_; i += 512) {
      int b = i / FSTRIDE_, d = i - (i / FSTRIDE_) * FSTRIDE_;
      flat[((size_t)b * RPB_ + HW_) * FSTRIDE_ + d] = (d == 132) ? 0x3F80 : 0;
    }
    return;
  }
  int b = bid >> 7, h = bid & 127;

  __shared__ __align__(16) float in_s[9][132];
  __shared__ float parts[8][132];
  __shared__ float nscale[132];

  for (int i = tid; i < 9 * 132; i += 512) {
    int ck = i / 132, x = i - ck * 132;
    int c = ck / 3, kh = ck - c * 3;
    int hh = h + kh - 1, ww = x - 1;
    float val = 0.f;
    if (x >= 1 && x <= 128 && hh >= 0 && hh < H_)
      val = img[((size_t)(b * C_ + c) * H_ + hh) * W_ + ww];
    in_s[ck][x] = val;
  }
  __syncthreads();

  // conv for one (wg,d) item: 16 outputs w = wg*16 + 0..15
  auto conv16 = [&](int item, float* acc) {
    int wg = item / 132;
    int d = item - wg * 132;
    float bias = cb[d];
    const float* wp = cw + d * 27;
    float wt[27];
#pragma unroll
    for (int j = 0; j < 27; ++j) wt[j] = wp[j];
#pragma unroll
    for (int i = 0; i < 16; ++i) acc[i] = bias;
    int q = wg * 4;  // float4 index of w0 = wg*16
#pragma unroll
    for (int ck = 0; ck < 9; ++ck) {
      const float4* p4 = (const float4*)&in_s[ck][0];
      float v[20];
#pragma unroll
      for (int j = 0; j < 5; ++j) {
        float4 t4 = p4[q + j];  // wave-broadcast (wg uniform per wave mostly)
        v[4 * j + 0] = t4.x; v[4 * j + 1] = t4.y;
        v[4 * j + 2] = t4.z; v[4 * j + 3] = t4.w;
      }
#pragma unroll
      for (int i = 0; i < 16; ++i) {
        float a0 = fmaf(v[i], wt[ck * 3 + 0], acc[i]);
        float a1 = fmaf(v[i + 1], wt[ck * 3 + 1], a0);
        acc[i] = fmaf(v[i + 2], wt[ck * 3 + 2], a1);
      }
    }
    float ssq = 0.f;
#pragma unroll
    for (int i = 0; i < 16; ++i) ssq = fmaf(acc[i], acc[i], ssq);
    parts[wg][d] = ssq;
  };

  float acc0[16], acc1[16], acc2[16];
  conv16(tid, acc0);
  conv16(tid + 512, acc1);
  if (tid < 32) conv16(tid + 1024, acc2);
  __syncthreads();

  if (tid < 132) {
    float s = 0.f;
#pragma unroll
    for (int wg = 0; wg < 8; ++wg) s += parts[wg][tid];
    nscale[tid] = 1.f / fmaxf(sqrtf(s), 1e-12f);
  }
  __syncthreads();

  size_t rowbase = (size_t)b * RPB_ + (size_t)h * W_;
  auto store16 = [&](int item, const float* acc) {
    int wg = item / 132;
    int d = item - wg * 132;
    float sc = nscale[d];
#pragma unroll
    for (int i = 0; i < 16; ++i)
      flat[(rowbase + wg * 16 + i) * FSTRIDE_ + d] = f2bf(acc[i] * sc);
  };
  store16(tid, acc0);
  store16(tid + 512, acc1);
  if (tid < 32) store16(tid + 1024, acc2);

  // cols 132..135 of each of this block's 128 rows: [1.0, 0, 0, 0] (8 B aligned)
  if (tid < 128) {
    uint2 tailv; tailv.x = 0x3F80u; tailv.y = 0u;
    *(uint2*)&flat[(rowbase + tid) * FSTRIDE_ + 132] = tailv;
  }
}

// ---------------------------------------------------------------------------
// K2: MFMA GEMM -> bf16 z_ext rows [z(132), sv+c, 1.0, 0, 0], and writes
// su back into flat_ext col 133. (unchanged from round 5)
// ---------------------------------------------------------------------------
__global__ __launch_bounds__(256, 2) void gemm_kernel(
    unsigned short* __restrict__ fb, const unsigned short* __restrict__ Mb,
    const float* __restrict__ cc, unsigned short* __restrict__ zb) {
  __shared__ __align__(16) unsigned short As[64 * FSTRIDE_ + 64];  // +tail pad
  __shared__ __align__(16) unsigned short Ms[MELEMS_];
  int tid = threadIdx.x, wave = tid >> 6, lane = tid & 63;
  size_t row0 = (size_t)blockIdx.x * 64;

  for (int ch = wave; ch < 48; ch += 4)
    GLOAD16(Mb + (size_t)ch * 512 + lane * 8, Ms + ch * 512);
  const unsigned short* Ag = fb + row0 * FSTRIDE_;
  for (int ch = wave; ch < 17; ch += 4)
    GLOAD16(Ag + (size_t)ch * 512 + lane * 8, As + ch * 512);
  if (tid < 64) As[64 * FSTRIDE_ + tid] = 0;  // tail: slice-5 OOB reads
  __syncthreads();

  int c15 = lane & 15, kg = lane >> 4;
  const unsigned short* arow = &As[(wave * 16 + c15) * FSTRIDE_ + kg * 8];
  const unsigned short* brow = &Ms[c15 * MSTRIDE_ + kg * 8];
  f32x4 acc[9] = {};
#pragma unroll
  for (int ks = 0; ks < 5; ++ks) {
    short8v af = *(const short8v*)(arow + ks * 32);
#pragma unroll
    for (int ct = 0; ct < 9; ++ct) {
      short8v bf = *(const short8v*)(brow + ct * 16 * MSTRIDE_ + ks * 32);
      acc[ct] = __builtin_amdgcn_mfma_f32_16x16x32_bf16(af, bf, acc[ct], 0, 0, 0);
    }
  }

  float cval = cc[0];
  size_t rbase = row0 + wave * 16 + kg * 4;
#pragma unroll
  for (int ct = 0; ct < 9; ++ct) {
    int col = ct * 16 + c15;
#pragma unroll
    for (int j = 0; j < 4; ++j) {
      size_t r = rbase + j;
      if (r < NROWS_) {
        if (col < D_)            zb[r * FSTRIDE_ + col] = f2bf(acc[ct][j]);
        else if (col == 132)     fb[r * FSTRIDE_ + 133] = f2bf(acc[ct][j]);        // su
        else if (col == 133)     zb[r * FSTRIDE_ + 132] = f2bf(acc[ct][j] + cval); // sv+c
        else if (col == 134)     zb[r * FSTRIDE_ + 133] = 0x3F80;                  // 1.0
        else if (col == 135)     zb[r * FSTRIDE_ + 134] = 0;
        else if (col == 136)     zb[r * FSTRIDE_ + 135] = 0;
      }
    }
  }
}

// ---------------------------------------------------------------------------
// K3 v2: gather + dot, 2 outputs per thread (o and o+NOUT_/2) for 2x MLP.
// 8 lanes per output; out = (fx_ext . zy_ext) * 132^-0.5
// ---------------------------------------------------------------------------
__global__ __launch_bounds__(256) void gather_kernel(
    const int* __restrict__ xi, const int* __restrict__ yi,
    const unsigned short* __restrict__ flat, const unsigned short* __restrict__ zb,
    float* __restrict__ out) {
  const float scale = 0.08703882797784892f;  // 132^-0.5
  int o1 = blockIdx.x * 32 + (threadIdx.x >> 3);
  int o2 = o1 + NOUT_ / 2;
  int lane = threadIdx.x & 7;

  int b1 = o1 >> 16, r1 = o1 & 65535;
  int b2 = o2 >> 16, r2 = o2 & 65535;
  int x1 = xi[(size_t)b1 * NK_ + r1], y1 = yi[(size_t)b1 * NK_ + r1];
  int x2 = xi[(size_t)b2 * NK_ + r2], y2 = yi[(size_t)b2 * NK_ + r2];
  const unsigned short* fx1 = flat + ((size_t)b1 * RPB_ + x1) * FSTRIDE_;
  const unsigned short* zy1 = zb + ((size_t)b1 * RPB_ + y1) * FSTRIDE_;
  const unsigned short* fx2 = flat + ((size_t)b2 * RPB_ + x2) * FSTRIDE_;
  const unsigned short* zy2 = zb + ((size_t)b2 * RPB_ + y2) * FSTRIDE_;

  int e0 = lane * 8, e1 = 64 + lane * 8;
  // issue all row loads up front (8-12 independent 16-B loads in flight)
  ushort8v a10 = *(const ushort8v*)(fx1 + e0);
  ushort8v a11 = *(const ushort8v*)(fx1 + e1);
  ushort8v z10 = *(const ushort8v*)(zy1 + e0);
  ushort8v z11 = *(const ushort8v*)(zy1 + e1);
  ushort8v a20 = *(const ushort8v*)(fx2 + e0);
  ushort8v a21 = *(const ushort8v*)(fx2 + e1);
  ushort8v z20 = *(const ushort8v*)(zy2 + e0);
  ushort8v z21 = *(const ushort8v*)(zy2 + e1);
  ushort8v a1t, z1t, a2t, z2t;
  if (lane == 0) {
    a1t = *(const ushort8v*)(fx1 + 128);
    z1t = *(const ushort8v*)(zy1 + 128);
    a2t = *(const ushort8v*)(fx2 + 128);
    z2t = *(const ushort8v*)(zy2 + 128);
  }

  float acc1 = 0.f, acc2 = 0.f;
#pragma unroll
  for (int t = 0; t < 8; ++t) {
    acc1 = fmaf(bf2f(a10[t]), bf2f(z10[t]), acc1);
    acc2 = fmaf(bf2f(a20[t]), bf2f(z20[t]), acc2);
  }
#pragma unroll
  for (int t = 0; t < 8; ++t) {
    acc1 = fmaf(bf2f(a11[t]), bf2f(z11[t]), acc1);
    acc2 = fmaf(bf2f(a21[t]), bf2f(z21[t]), acc2);
  }
  if (lane == 0) {  // elems 128..135: real 128..131 + (1)(sv+c) + (su)(1) + 0s
#pragma unroll
    for (int t = 0; t < 8; ++t) {
      acc1 = fmaf(bf2f(a1t[t]), bf2f(z1t[t]), acc1);
      acc2 = fmaf(bf2f(a2t[t]), bf2f(z2t[t]), acc2);
    }
  }
  acc1 += __shfl_xor(acc1, 1);
  acc2 += __shfl_xor(acc2, 1);
  acc1 += __shfl_xor(acc1, 2);
  acc2 += __shfl_xor(acc2, 2);
  acc1 += __shfl_xor(acc1, 4);
  acc2 += __shfl_xor(acc2, 4);
  if (lane == 0) {
    out[o1] = acc1 * scale;
    out[o2] = acc2 * scale;
  }
}

// ---------------------------------------------------------------------------
extern "C" void kernel_launch(void* const* d_in, const int* in_sizes, int n_in,
                              void* d_out, int out_size, void* d_ws, size_t ws_size,
                              hipStream_t stream) {
  const int* indices  = (const int*)d_in[0];
  const float* img    = (const float*)d_in[1];
  const float* conv_w = (const float*)d_in[2];
  const float* conv_b = (const float*)d_in[3];
  const float* ks_w   = (const float*)d_in[4];
  const float* ks_b   = (const float*)d_in[5];
  const float* qs_w   = (const float*)d_in[6];
  const float* qs_b   = (const float*)d_in[7];
  float* out = (float*)d_out;

  // workspace layout (~71.5 MB)
  char* w = (char*)d_ws;
  unsigned short* flatb = (unsigned short*)w;                  // AROWS_*136 bf16
  size_t off = (size_t)AROWS_ * FSTRIDE_ * 2;
  unsigned short* zbuf = (unsigned short*)(w + off); off += (size_t)AROWS_ * FSTRIDE_ * 2;
  unsigned short* Mb = (unsigned short*)(w + off);   off += MELEMS_ * 2;
  float* cc = (float*)(w + off);

  const int* xi = indices + (size_t)B_ * NK_;      // indices[1]
  const int* yi = indices + (size_t)2 * B_ * NK_;  // indices[2]

  hipLaunchKernelGGL(prep_kernel, dim3(MELEMS_ / 256), dim3(256), 0, stream,
                     ks_w, ks_b, qs_w, qs_b, Mb, cc);
  hipLaunchKernelGGL(conv_norm_kernel, dim3(B_ * H_ + 1), dim3(512), 0, stream,
                     img, conv_w, conv_b, flatb);
  hipLaunchKernelGGL(gemm_kernel, dim3(AROWS_ / 64), dim3(256), 0, stream,
                     flatb, Mb, cc, zbuf);
  hipLaunchKernelGGL(gather_kernel, dim3(NOUT_ / 64), dim3(256), 0, stream,
                     xi, yi, flatb, zbuf, out);
}

// Round 7
// 92.351 us; speedup vs baseline: 1.1575x; 1.1575x over previous
//
#include <hip/hip_runtime.h>
#include <hip/hip_bf16.h>
#include <math.h>

#define B_ 8
#define H_ 128
#define W_ 128
#define C_ 3
#define D_ 132
#define HW_ (H_*W_)            // 16384
#define RPB_ (HW_+1)           // 16385 rows per batch (incl. zero row)
#define NROWS_ (B_*RPB_)       // 131080
#define AROWS_ 131136          // 2049*64, slack so last tile can stage
#define FSTRIDE_ 136           // bf16 row stride for flat_ext AND z_ext (272 B)
#define MSTRIDE_ 168           // M row stride (zeros at k>=132)
#define NK_ 65536
#define NOUT_ (B_*NK_)         // 524288
#define MELEMS_ 24576          // M buffer elems (49152 B = 48 chunks of 1 KiB)

typedef __attribute__((ext_vector_type(8))) short short8v;
typedef __attribute__((ext_vector_type(8))) unsigned short ushort8v;
typedef __attribute__((ext_vector_type(4))) float f32x4;

#define GLOAD16(gp, lp) __builtin_amdgcn_global_load_lds( \
  (const __attribute__((address_space(1))) unsigned int*)(gp), \
  (__attribute__((address_space(3))) unsigned int*)(void*)(lp), 16, 0, 0)

__device__ inline float bf2f(unsigned short u) {
  return __uint_as_float(((unsigned)u) << 16);
}
__device__ inline unsigned short f2bf(float f) {
  __hip_bfloat16 hb = __float2bfloat16(f);
  return *(unsigned short*)&hb;
}

// ---------------------------------------------------------------------------
// K1 (fused): blocks [0,1024) conv rows; block 1024 zero-rows; blocks
// [1025,1073) prep of M_bf16 [146][168] + c.
// conv: 512 threads, 1056 items of (wg 0..7 x d 0..131), item = wg*132+d.
// Thread t does items {t, t+512, t+1024 if t<32}, 16 w-outputs each.
// Weights staged in LDS (stride-27 reads: 27 coprime 32 -> conflict-free).
// ---------------------------------------------------------------------------
__global__ __launch_bounds__(512, 4) void fused_prep_conv_kernel(
    const float* __restrict__ img, const float* __restrict__ cw,
    const float* __restrict__ cb, unsigned short* __restrict__ flat,
    const float* __restrict__ ks_w, const float* __restrict__ ks_b,
    const float* __restrict__ qs_w, const float* __restrict__ qs_b,
    unsigned short* __restrict__ Mb, float* __restrict__ cc) {
  int bid = blockIdx.x;
  int tid = threadIdx.x;

  if (bid > B_ * H_) {
    // ---- prep part: 48 blocks x 512 = 24576 threads, one elem each ----
    int idx = (bid - (B_ * H_ + 1)) * 512 + tid;
    if (idx >= MELEMS_) return;
    int a = idx / MSTRIDE_;
    int k = idx - a * MSTRIDE_;
    float val = 0.f;
    if (k < D_) {
      if (a < D_) {
        for (int o = 0; o < D_; ++o)
          val = fmaf(ks_w[o * D_ + a], qs_w[o * D_ + k], val);
      } else if (a == 132) {
        for (int o = 0; o < D_; ++o)
          val = fmaf(qs_b[o], ks_w[o * D_ + k], val);
      } else if (a == 133) {
        for (int o = 0; o < D_; ++o)
          val = fmaf(ks_b[o], qs_w[o * D_ + k], val);
      }
    }
    Mb[idx] = f2bf(val);
    if (idx == 0) {
      float s = 0.f;
      for (int o = 0; o < D_; ++o) s = fmaf(ks_b[o], qs_b[o], s);
      cc[0] = s;
    }
    return;
  }
  if (bid == B_ * H_) {
    // zero row 16384 of every batch: [0 x132, 1.0, 0, 0, 0]
    for (int i = tid; i < B_ * FSTRIDE_; i += 512) {
      int b = i / FSTRIDE_, d = i - (i / FSTRIDE_) * FSTRIDE_;
      flat[((size_t)b * RPB_ + HW_) * FSTRIDE_ + d] = (d == 132) ? 0x3F80 : 0;
    }
    return;
  }
  int b = bid >> 7, h = bid & 127;

  __shared__ __align__(16) float in_s[9][132];
  __shared__ float w_s[D_ * 27];      // 14256 B
  __shared__ float b_s[D_];
  __shared__ float parts[8][132];
  __shared__ float nscale[132];

  for (int i = tid; i < 9 * 132; i += 512) {
    int ck = i / 132, x = i - ck * 132;
    int c = ck / 3, kh = ck - c * 3;
    int hh = h + kh - 1, ww = x - 1;
    float val = 0.f;
    if (x >= 1 && x <= 128 && hh >= 0 && hh < H_)
      val = img[((size_t)(b * C_ + c) * H_ + hh) * W_ + ww];
    in_s[ck][x] = val;
  }
  for (int i = tid; i < D_ * 27; i += 512) w_s[i] = cw[i];
  if (tid < D_) b_s[tid] = cb[tid];
  __syncthreads();

  // conv for one (wg,d) item: 16 outputs w = wg*16 + 0..15
  auto conv16 = [&](int item, float* acc) {
    int wg = item / 132;
    int d = item - wg * 132;
    float wt[27];
#pragma unroll
    for (int j = 0; j < 27; ++j) wt[j] = w_s[d * 27 + j];  // LDS, conflict-free
    float bias = b_s[d];
#pragma unroll
    for (int i = 0; i < 16; ++i) acc[i] = bias;
    int q = wg * 4;  // float4 index of w0 = wg*16
#pragma unroll
    for (int ck = 0; ck < 9; ++ck) {
      const float4* p4 = (const float4*)&in_s[ck][0];
      float v[20];
#pragma unroll
      for (int j = 0; j < 5; ++j) {
        float4 t4 = p4[q + j];  // wave-broadcast
        v[4 * j + 0] = t4.x; v[4 * j + 1] = t4.y;
        v[4 * j + 2] = t4.z; v[4 * j + 3] = t4.w;
      }
#pragma unroll
      for (int i = 0; i < 16; ++i) {
        float a0 = fmaf(v[i], wt[ck * 3 + 0], acc[i]);
        float a1 = fmaf(v[i + 1], wt[ck * 3 + 1], a0);
        acc[i] = fmaf(v[i + 2], wt[ck * 3 + 2], a1);
      }
    }
    float ssq = 0.f;
#pragma unroll
    for (int i = 0; i < 16; ++i) ssq = fmaf(acc[i], acc[i], ssq);
    parts[wg][d] = ssq;
  };

  float acc0[16], acc1[16], acc2[16];
  conv16(tid, acc0);
  conv16(tid + 512, acc1);
  if (tid < 32) conv16(tid + 1024, acc2);
  __syncthreads();

  if (tid < 132) {
    float s = 0.f;
#pragma unroll
    for (int wg = 0; wg < 8; ++wg) s += parts[wg][tid];
    nscale[tid] = 1.f / fmaxf(sqrtf(s), 1e-12f);
  }
  __syncthreads();

  size_t rowbase = (size_t)b * RPB_ + (size_t)h * W_;
  auto store16 = [&](int item, const float* acc) {
    int wg = item / 132;
    int d = item - wg * 132;
    float sc = nscale[d];
#pragma unroll
    for (int i = 0; i < 16; ++i)
      flat[(rowbase + wg * 16 + i) * FSTRIDE_ + d] = f2bf(acc[i] * sc);
  };
  store16(tid, acc0);
  store16(tid + 512, acc1);
  if (tid < 32) store16(tid + 1024, acc2);

  // cols 132..135 of each of this block's 128 rows: [1.0, 0, 0, 0]
  if (tid < 128) {
    uint2 tailv; tailv.x = 0x3F80u; tailv.y = 0u;
    *(uint2*)&flat[(rowbase + tid) * FSTRIDE_ + 132] = tailv;
  }
}

// ---------------------------------------------------------------------------
// K2: MFMA GEMM -> bf16 z_ext rows [z(132), sv+c, 1.0, 0, 0], and writes
// su back into flat_ext col 133. (unchanged)
// ---------------------------------------------------------------------------
__global__ __launch_bounds__(256, 2) void gemm_kernel(
    unsigned short* __restrict__ fb, const unsigned short* __restrict__ Mb,
    const float* __restrict__ cc, unsigned short* __restrict__ zb) {
  __shared__ __align__(16) unsigned short As[64 * FSTRIDE_ + 64];  // +tail pad
  __shared__ __align__(16) unsigned short Ms[MELEMS_];
  int tid = threadIdx.x, wave = tid >> 6, lane = tid & 63;
  size_t row0 = (size_t)blockIdx.x * 64;

  for (int ch = wave; ch < 48; ch += 4)
    GLOAD16(Mb + (size_t)ch * 512 + lane * 8, Ms + ch * 512);
  const unsigned short* Ag = fb + row0 * FSTRIDE_;
  for (int ch = wave; ch < 17; ch += 4)
    GLOAD16(Ag + (size_t)ch * 512 + lane * 8, As + ch * 512);
  if (tid < 64) As[64 * FSTRIDE_ + tid] = 0;  // tail: slice-5 OOB reads
  __syncthreads();

  int c15 = lane & 15, kg = lane >> 4;
  const unsigned short* arow = &As[(wave * 16 + c15) * FSTRIDE_ + kg * 8];
  const unsigned short* brow = &Ms[c15 * MSTRIDE_ + kg * 8];
  f32x4 acc[9] = {};
#pragma unroll
  for (int ks = 0; ks < 5; ++ks) {
    short8v af = *(const short8v*)(arow + ks * 32);
#pragma unroll
    for (int ct = 0; ct < 9; ++ct) {
      short8v bf = *(const short8v*)(brow + ct * 16 * MSTRIDE_ + ks * 32);
      acc[ct] = __builtin_amdgcn_mfma_f32_16x16x32_bf16(af, bf, acc[ct], 0, 0, 0);
    }
  }

  float cval = cc[0];
  size_t rbase = row0 + wave * 16 + kg * 4;
#pragma unroll
  for (int ct = 0; ct < 9; ++ct) {
    int col = ct * 16 + c15;
#pragma unroll
    for (int j = 0; j < 4; ++j) {
      size_t r = rbase + j;
      if (r < NROWS_) {
        if (col < D_)            zb[r * FSTRIDE_ + col] = f2bf(acc[ct][j]);
        else if (col == 132)     fb[r * FSTRIDE_ + 133] = f2bf(acc[ct][j]);        // su
        else if (col == 133)     zb[r * FSTRIDE_ + 132] = f2bf(acc[ct][j] + cval); // sv+c
        else if (col == 134)     zb[r * FSTRIDE_ + 133] = 0x3F80;                  // 1.0
        else if (col == 135)     zb[r * FSTRIDE_ + 134] = 0;
        else if (col == 136)     zb[r * FSTRIDE_ + 135] = 0;
      }
    }
  }
}

// ---------------------------------------------------------------------------
// K3 v4: gather + dot (round-5 body) + XCD batch-affinity swizzle:
// batch = blockIdx & 7 so each XCD (round-robin dispatch) works one batch's
// 8.9 MB flat+z slice -> L2 locality. 8 lanes per output.
// ---------------------------------------------------------------------------
__global__ __launch_bounds__(256) void gather_kernel(
    const int* __restrict__ xi, const int* __restrict__ yi,
    const unsigned short* __restrict__ flat, const unsigned short* __restrict__ zb,
    float* __restrict__ out) {
  const float scale = 0.08703882797784892f;  // 132^-0.5
  int bi = blockIdx.x;
  int b = bi & 7;                  // batch == XCD (round-robin dispatch)
  int chunk = bi >> 3;             // [0, 2048)
  int rem = chunk * 32 + (threadIdx.x >> 3);
  int lane = threadIdx.x & 7;
  size_t ib = (size_t)b * NK_ + rem;
  int x = xi[ib], y = yi[ib];
  const unsigned short* fx = flat + ((size_t)b * RPB_ + x) * FSTRIDE_;
  const unsigned short* zy = zb + ((size_t)b * RPB_ + y) * FSTRIDE_;
  float acc = 0.f;
#pragma unroll
  for (int leg = 0; leg < 2; ++leg) {
    int e0 = leg * 64 + lane * 8;
    ushort8v a8 = *(const ushort8v*)(fx + e0);
    ushort8v z8 = *(const ushort8v*)(zy + e0);
#pragma unroll
    for (int t = 0; t < 8; ++t)
      acc = fmaf(bf2f(a8[t]), bf2f(z8[t]), acc);
  }
  if (lane == 0) {  // elems 128..135: real 128..131 + (1)(sv+c) + (su)(1) + 0s
    ushort8v a8 = *(const ushort8v*)(fx + 128);
    ushort8v z8 = *(const ushort8v*)(zy + 128);
#pragma unroll
    for (int t = 0; t < 8; ++t)
      acc = fmaf(bf2f(a8[t]), bf2f(z8[t]), acc);
  }
  acc += __shfl_xor(acc, 1);
  acc += __shfl_xor(acc, 2);
  acc += __shfl_xor(acc, 4);
  if (lane == 0)
    out[((size_t)b << 16) | rem] = acc * scale;
}

// ---------------------------------------------------------------------------
extern "C" void kernel_launch(void* const* d_in, const int* in_sizes, int n_in,
                              void* d_out, int out_size, void* d_ws, size_t ws_size,
                              hipStream_t stream) {
  const int* indices  = (const int*)d_in[0];
  const float* img    = (const float*)d_in[1];
  const float* conv_w = (const float*)d_in[2];
  const float* conv_b = (const float*)d_in[3];
  const float* ks_w   = (const float*)d_in[4];
  const float* ks_b   = (const float*)d_in[5];
  const float* qs_w   = (const float*)d_in[6];
  const float* qs_b   = (const float*)d_in[7];
  float* out = (float*)d_out;

  // workspace layout (~71.5 MB)
  char* w = (char*)d_ws;
  unsigned short* flatb = (unsigned short*)w;                  // AROWS_*136 bf16
  size_t off = (size_t)AROWS_ * FSTRIDE_ * 2;
  unsigned short* zbuf = (unsigned short*)(w + off); off += (size_t)AROWS_ * FSTRIDE_ * 2;
  unsigned short* Mb = (unsigned short*)(w + off);   off += MELEMS_ * 2;
  float* cc = (float*)(w + off);

  const int* xi = indices + (size_t)B_ * NK_;      // indices[1]
  const int* yi = indices + (size_t)2 * B_ * NK_;  // indices[2]

  // blocks: [0,1024) conv, 1024 zero-rows, [1025, 1025+48) prep
  hipLaunchKernelGGL(fused_prep_conv_kernel, dim3(B_ * H_ + 1 + MELEMS_ / 512),
                     dim3(512), 0, stream,
                     img, conv_w, conv_b, flatb, ks_w, ks_b, qs_w, qs_b, Mb, cc);
  hipLaunchKernelGGL(gemm_kernel, dim3(AROWS_ / 64), dim3(256), 0, stream,
                     flatb, Mb, cc, zbuf);
  hipLaunchKernelGGL(gather_kernel, dim3(NOUT_ / 32), dim3(256), 0, stream,
                     xi, yi, flatb, zbuf, out);
}

// Round 10
// 90.280 us; speedup vs baseline: 1.1841x; 1.0229x over previous
//
#include <hip/hip_runtime.h>
#include <hip/hip_bf16.h>
#include <math.h>

#define B_ 8
#define H_ 128
#define W_ 128
#define C_ 3
#define D_ 132
#define HW_ (H_*W_)            // 16384
#define RPB_ (HW_+1)           // 16385 rows per batch (incl. zero row)
#define NROWS_ (B_*RPB_)       // 131080
#define AROWS_ 131136
#define FSTRIDE_ 136           // bf16 row stride for flat_ext AND z_ext (272 B)
#define MSTRIDE_ 160           // compact M stride (col 0..159, zero >=132)
#define MROWS_ 144
#define MELEMS_ (MROWS_*MSTRIDE_)   // 23040 elems = 46080 B = 45 KiB
#define NK_ 65536
#define NOUT_ (B_*NK_)         // 524288

typedef __attribute__((ext_vector_type(8))) short short8v;
typedef __attribute__((ext_vector_type(8))) unsigned short ushort8v;
typedef __attribute__((ext_vector_type(4))) float f32x4;

#define GLOAD16(gp, lp) __builtin_amdgcn_global_load_lds( \
  (const __attribute__((address_space(1))) unsigned int*)(gp), \
  (__attribute__((address_space(3))) unsigned int*)(void*)(lp), 16, 0, 0)

__device__ inline float bf2f(unsigned short u) {
  return __uint_as_float(((unsigned)u) << 16);
}
__device__ inline unsigned short f2bf(float f) {
  __hip_bfloat16 hb = __float2bfloat16(f);
  return *(unsigned short*)&hb;
}

// ---------------------------------------------------------------------------
// K0: compact M_bf16 [144][160]: a<132 -> Ks^T Qs; a==132 -> u (su row);
// a==133 -> v (sv row); else 0. Cols >=132 zero. c = ks_b . qs_b.
// ---------------------------------------------------------------------------
__global__ __launch_bounds__(512) void prep_kernel(
    const float* __restrict__ ks_w, const float* __restrict__ ks_b,
    const float* __restrict__ qs_w, const float* __restrict__ qs_b,
    unsigned short* __restrict__ Mb, float* __restrict__ cc) {
  int idx = blockIdx.x * 512 + threadIdx.x;
  if (idx >= MELEMS_) return;
  int a = idx / MSTRIDE_;
  int k = idx - a * MSTRIDE_;
  float val = 0.f;
  if (k < D_) {
    if (a < D_) {
      for (int o = 0; o < D_; ++o)
        val = fmaf(ks_w[o * D_ + a], qs_w[o * D_ + k], val);
    } else if (a == 132) {
      for (int o = 0; o < D_; ++o)
        val = fmaf(qs_b[o], ks_w[o * D_ + k], val);
    } else if (a == 133) {
      for (int o = 0; o < D_; ++o)
        val = fmaf(ks_b[o], qs_w[o * D_ + k], val);
    }
  }
  Mb[idx] = f2bf(val);
  if (idx == 0) {
    float s = 0.f;
    for (int o = 0; o < D_; ++o) s = fmaf(ks_b[o], qs_b[o], s);
    cc[0] = s;
  }
}

// ---------------------------------------------------------------------------
// conv helper: one (d, w0) item -> 16 conv outputs + partial ssq
// ---------------------------------------------------------------------------
__device__ __forceinline__ float conv_item16(
    const float* __restrict__ in_s, const float* __restrict__ w_s,
    float bias, int d, int w0, float* acc) {
  float wt[27];
#pragma unroll
  for (int j = 0; j < 27; ++j) wt[j] = w_s[d * 27 + j];
#pragma unroll
  for (int i = 0; i < 16; ++i) acc[i] = bias;
#pragma unroll
  for (int ck = 0; ck < 9; ++ck) {
    const float4* p4 = (const float4*)(in_s + ck * 132);
    float v[20];
#pragma unroll
    for (int j = 0; j < 5; ++j) {
      float4 t4 = p4[(w0 >> 2) + j];   // wave-broadcast reads
      v[4 * j + 0] = t4.x; v[4 * j + 1] = t4.y;
      v[4 * j + 2] = t4.z; v[4 * j + 3] = t4.w;
    }
#pragma unroll
    for (int i = 0; i < 16; ++i) {
      float a0 = fmaf(v[i], wt[ck * 3 + 0], acc[i]);
      float a1 = fmaf(v[i + 1], wt[ck * 3 + 1], a0);
      acc[i] = fmaf(v[i + 2], wt[ck * 3 + 2], a1);
    }
  }
  float ssq = 0.f;
#pragma unroll
  for (int i = 0; i < 16; ++i) ssq = fmaf(acc[i], acc[i], ssq);
  return ssq;
}

// ---------------------------------------------------------------------------
// K1 fused conv+gemm, block bid<1024 owns 128 rows (b,h line):
//   phase A: conv+norm into regs (M staged to LDS meanwhile via gload_lds)
//   phase B: store flat_ext to GLOBAL only
//   restage: global_load_lds fb rows -> As (union; proven staging mechanism)
//   phase C: 8-wave MFMA z = f M^T -> z_ext bf16 + su into flat col 133.
// bid==1024: zero rows for all batches.
// LDS: Ms 46080 + nscale 528 + un 34880 = 81488 B <= 81920 -> 2 blocks/CU.
// ---------------------------------------------------------------------------
__global__ __launch_bounds__(512, 4) void fused_conv_gemm_kernel(
    const float* __restrict__ img, const float* __restrict__ cw,
    const float* __restrict__ cb, unsigned short* __restrict__ fb,
    const unsigned short* __restrict__ Mb, const float* __restrict__ cc,
    unsigned short* __restrict__ zb) {
  int bid = blockIdx.x;
  int tid = threadIdx.x;

  if (bid == B_ * H_) {
    // zero row 16384 of every batch
    float cval = cc[0];
    for (int i = tid; i < B_ * FSTRIDE_; i += 512) {
      int b = i / FSTRIDE_, d = i - (i / FSTRIDE_) * FSTRIDE_;
      size_t r = (size_t)b * RPB_ + HW_;
      fb[r * FSTRIDE_ + d] = (d == 132) ? 0x3F80 : 0;     // [0 x132, 1, su=0, 0, 0]
      unsigned short zv = 0;
      if (d == 132) zv = f2bf(cval);                      // sv+c = c
      else if (d == 133) zv = 0x3F80;                     // 1.0
      zb[r * FSTRIDE_ + d] = zv;
    }
    return;
  }

  int wave = tid >> 6, lane = tid & 63;
  __shared__ __align__(16) unsigned short Ms[MELEMS_];   // 46080 B
  __shared__ float nscale[132];                          // 528 B
  __shared__ __align__(16) char un[34880];               // union region
  float* in_s = (float*)un;            // 9*132 = 1188 f
  float* w_s  = in_s + 9 * 132;        // 132*27 = 3564 f
  float* b_s  = w_s + 132 * 27;        // 132 f
  float* parts = b_s + 132;            // 8*132 f  (total 23760 B < 34880)
  unsigned short* As = (unsigned short*)un;  // [128][136] + 32 pad (restage)

  // stage compact M (45 KiB) - drained by the phase-A barrier
  for (int ch = wave; ch < 45; ch += 8)
    GLOAD16(Mb + (size_t)ch * 512 + lane * 8, Ms + ch * 512);

  int b = bid >> 7, h = bid & 127;
  for (int i = tid; i < 9 * 132; i += 512) {
    int ck = i / 132, x = i - ck * 132;
    int c = ck / 3, kh = ck - c * 3;
    int hh = h + kh - 1, ww = x - 1;
    float val = 0.f;
    if (x >= 1 && x <= 128 && hh >= 0 && hh < H_)
      val = img[((size_t)(b * C_ + c) * H_ + hh) * W_ + ww];
    in_s[i] = val;
  }
  for (int i = tid; i < D_ * 27; i += 512) w_s[i] = cw[i];
  if (tid < D_) b_s[tid] = cb[tid];
  __syncthreads();

  // phase A: conv. Round-7-proven split: items {tid, tid+512, tid+1024 if
  // tid<32}, 16-wide each; item = wg*132 + d. Every parts entry written once.
  float acc0[16], acc1[16], acc2[16];
  int i0 = tid, i1 = tid + 512;
  int wg0 = i0 / 132, dd0 = i0 - wg0 * 132;
  int wg1 = i1 / 132, dd1 = i1 - wg1 * 132;
  parts[wg0 * 132 + dd0] = conv_item16(in_s, w_s, b_s[dd0], dd0, wg0 * 16, acc0);
  parts[wg1 * 132 + dd1] = conv_item16(in_s, w_s, b_s[dd1], dd1, wg1 * 16, acc1);
  int dd2 = 0;
  if (tid < 32) {
    dd2 = 100 + tid;                    // i2 = tid+1024 -> wg 7, d 100..131
    parts[7 * 132 + dd2] = conv_item16(in_s, w_s, b_s[dd2], dd2, 112, acc2);
  }
  __syncthreads();
  if (tid < 132) {
    float s = 0.f;
#pragma unroll
    for (int rr = 0; rr < 8; ++rr) s += parts[rr * 132 + tid];
    nscale[tid] = 1.f / fmaxf(sqrtf(s), 1e-12f);
  }
  __syncthreads();

  // phase B: store flat_ext to GLOBAL only (no LDS writes)
  size_t rowbase = (size_t)b * RPB_ + (size_t)h * W_;
  {
    float sc = nscale[dd0];
#pragma unroll
    for (int i = 0; i < 16; ++i)
      fb[(rowbase + wg0 * 16 + i) * FSTRIDE_ + dd0] = f2bf(acc0[i] * sc);
    sc = nscale[dd1];
#pragma unroll
    for (int i = 0; i < 16; ++i)
      fb[(rowbase + wg1 * 16 + i) * FSTRIDE_ + dd1] = f2bf(acc1[i] * sc);
  }
  if (tid < 32) {
    float sc = nscale[dd2];
#pragma unroll
    for (int i = 0; i < 16; ++i)
      fb[(rowbase + 112 + i) * FSTRIDE_ + dd2] = f2bf(acc2[i] * sc);
  }
  if (tid < 128) {  // row tails: cols 132..135 = [1.0, 0, 0, 0]
    uint2 tv; tv.x = 0x3F80u; tv.y = 0u;
    *(uint2*)&fb[(rowbase + tid) * FSTRIDE_ + 132] = tv;   // col133 su written in C
  }
  __syncthreads();  // drains global stores (vmcnt 0) -> L2-visible; un now dead

  // restage this block's 128 fb rows into As via global_load_lds (L2-hot)
  const unsigned short* Ag = fb + rowbase * FSTRIDE_;
  for (int ch = wave; ch < 34; ch += 8)
    GLOAD16(Ag + (size_t)ch * 512 + lane * 8, As + ch * 512);
  if (tid < 32) As[128 * FSTRIDE_ + tid] = 0;  // wrap pad for K-slice 5
  __syncthreads();

  // phase C: MFMA. wave w: rows w*16..w*16+15, 9 col-tiles, K = 5 slices.
  int c15 = lane & 15, kg = lane >> 4;
  const unsigned short* arow = As + (wave * 16 + c15) * FSTRIDE_ + kg * 8;
  const unsigned short* brow = Ms + c15 * MSTRIDE_ + kg * 8;
  f32x4 acc[9] = {};
#pragma unroll
  for (int ks = 0; ks < 5; ++ks) {
    short8v af = *(const short8v*)(arow + ks * 32);
#pragma unroll
    for (int ct = 0; ct < 9; ++ct) {
      short8v bf = *(const short8v*)(brow + ct * 16 * MSTRIDE_ + ks * 32);
      acc[ct] = __builtin_amdgcn_mfma_f32_16x16x32_bf16(af, bf, acc[ct], 0, 0, 0);
    }
  }
  float cval = cc[0];
  size_t rbase = rowbase + wave * 16 + kg * 4;   // global row (incl. zero rows)
#pragma unroll
  for (int ct = 0; ct < 9; ++ct) {
    int col = ct * 16 + c15;
#pragma unroll
    for (int j = 0; j < 4; ++j) {
      size_t r = rbase + j;
      if (col < D_)            zb[r * FSTRIDE_ + col] = f2bf(acc[ct][j]);
      else if (col == 132)     fb[r * FSTRIDE_ + 133] = f2bf(acc[ct][j]);        // su
      else if (col == 133)     zb[r * FSTRIDE_ + 132] = f2bf(acc[ct][j] + cval); // sv+c
      else if (col == 134)     zb[r * FSTRIDE_ + 133] = 0x3F80;                  // 1.0
      else if (col == 135)     zb[r * FSTRIDE_ + 134] = 0;
      else if (col == 136)     zb[r * FSTRIDE_ + 135] = 0;
    }
  }
}

// ---------------------------------------------------------------------------
// K3: gather + dot with XCD batch-affinity swizzle (batch = blockIdx & 7).
// 8 lanes per output; out = (fx_ext . zy_ext) * 132^-0.5
// ---------------------------------------------------------------------------
__global__ __launch_bounds__(256) void gather_kernel(
    const int* __restrict__ xi, const int* __restrict__ yi,
    const unsigned short* __restrict__ flat, const unsigned short* __restrict__ zb,
    float* __restrict__ out) {
  const float scale = 0.08703882797784892f;  // 132^-0.5
  int bi = blockIdx.x;
  int b = bi & 7;
  int chunk = bi >> 3;
  int rem = chunk * 32 + (threadIdx.x >> 3);
  int lane = threadIdx.x & 7;
  size_t ib = (size_t)b * NK_ + rem;
  int x = xi[ib], y = yi[ib];
  const unsigned short* fx = flat + ((size_t)b * RPB_ + x) * FSTRIDE_;
  const unsigned short* zy = zb + ((size_t)b * RPB_ + y) * FSTRIDE_;
  float acc = 0.f;
#pragma unroll
  for (int leg = 0; leg < 2; ++leg) {
    int e0 = leg * 64 + lane * 8;
    ushort8v a8 = *(const ushort8v*)(fx + e0);
    ushort8v z8 = *(const ushort8v*)(zy + e0);
#pragma unroll
    for (int t = 0; t < 8; ++t)
      acc = fmaf(bf2f(a8[t]), bf2f(z8[t]), acc);
  }
  if (lane == 0) {  // elems 128..135: real 128..131 + (1)(sv+c) + (su)(1) + 0s
    ushort8v a8 = *(const ushort8v*)(fx + 128);
    ushort8v z8 = *(const ushort8v*)(zy + 128);
#pragma unroll
    for (int t = 0; t < 8; ++t)
      acc = fmaf(bf2f(a8[t]), bf2f(z8[t]), acc);
  }
  acc += __shfl_xor(acc, 1);
  acc += __shfl_xor(acc, 2);
  acc += __shfl_xor(acc, 4);
  if (lane == 0)
    out[((size_t)b << 16) | rem] = acc * scale;
}

// ---------------------------------------------------------------------------
extern "C" void kernel_launch(void* const* d_in, const int* in_sizes, int n_in,
                              void* d_out, int out_size, void* d_ws, size_t ws_size,
                              hipStream_t stream) {
  const int* indices  = (const int*)d_in[0];
  const float* img    = (const float*)d_in[1];
  const float* conv_w = (const float*)d_in[2];
  const float* conv_b = (const float*)d_in[3];
  const float* ks_w   = (const float*)d_in[4];
  const float* ks_b   = (const float*)d_in[5];
  const float* qs_w   = (const float*)d_in[6];
  const float* qs_b   = (const float*)d_in[7];
  float* out = (float*)d_out;

  // workspace layout (~71.4 MB)
  char* w = (char*)d_ws;
  unsigned short* flatb = (unsigned short*)w;                  // AROWS_*136 bf16
  size_t off = (size_t)AROWS_ * FSTRIDE_ * 2;
  unsigned short* zbuf = (unsigned short*)(w + off); off += (size_t)AROWS_ * FSTRIDE_ * 2;
  unsigned short* Mb = (unsigned short*)(w + off);   off += MELEMS_ * 2;
  float* cc = (float*)(w + off);

  const int* xi = indices + (size_t)B_ * NK_;      // indices[1]
  const int* yi = indices + (size_t)2 * B_ * NK_;  // indices[2]

  hipLaunchKernelGGL(prep_kernel, dim3(MELEMS_ / 512), dim3(512), 0, stream,
                     ks_w, ks_b, qs_w, qs_b, Mb, cc);
  hipLaunchKernelGGL(fused_conv_gemm_kernel, dim3(B_ * H_ + 1), dim3(512), 0, stream,
                     img, conv_w, conv_b, flatb, Mb, cc, zbuf);
  hipLaunchKernelGGL(gather_kernel, dim3(NOUT_ / 32), dim3(256), 0, stream,
                     xi, yi, flatb, zbuf, out);
}